// Round 3
// baseline (1850.781 us; speedup 1.0000x reference)
//
// round 2: identical to round 0/1 (infra retry — UnresponsiveContainer x2, same pod)
#include <hip/hip_runtime.h>
#include <math.h>

#define NROW 4096
#define ALPHA_SLOPE 0.2f

// ---------------- generic f32 GEMM: C[M,Nc] = A[M,K] @ B[K,Nc], row-major ----------------
// 64x64 tile, 256 threads, 4x4 register micro-tile, BK=16.
// Requires: M % 64 == 0, K % 16 == 0. Nc arbitrary (guarded).
__global__ __launch_bounds__(256)
void gemm_f32(const float* __restrict__ A, const float* __restrict__ B,
              float* __restrict__ C, int M, int Nc, int K)
{
    __shared__ float As[16][65];   // [k][m]
    __shared__ float Bs[16][65];   // [k][n]
    const int tid = threadIdx.x;
    const int tr = tid >> 4;       // 0..15
    const int tc = tid & 15;       // 0..15
    const int row0 = blockIdx.y * 64;
    const int col0 = blockIdx.x * 64;
    float acc[4][4] = {{0.f}};

    for (int k0 = 0; k0 < K; k0 += 16) {
        // A tile: 64 rows x 16 k  (1024 floats, 4 per thread via float4)
        {
            const int r  = tid >> 2;           // 0..63
            const int c4 = (tid & 3) * 4;      // 0,4,8,12
            const float* ap = A + (size_t)(row0 + r) * K + k0 + c4;
            const float4 v = *reinterpret_cast<const float4*>(ap);
            As[c4 + 0][r] = v.x;
            As[c4 + 1][r] = v.y;
            As[c4 + 2][r] = v.z;
            As[c4 + 3][r] = v.w;
        }
        // B tile: 16 k x 64 cols
        {
            const int kk = tid >> 4;           // 0..15
            const int c4 = (tid & 15) * 4;     // 0..60
            const float* bp = B + (size_t)(k0 + kk) * Nc + col0 + c4;
            float4 v;
            if (col0 + c4 + 3 < Nc) {
                v = *reinterpret_cast<const float4*>(bp);
            } else {
                v.x = (col0 + c4 + 0 < Nc) ? bp[0] : 0.f;
                v.y = (col0 + c4 + 1 < Nc) ? bp[1] : 0.f;
                v.z = (col0 + c4 + 2 < Nc) ? bp[2] : 0.f;
                v.w = (col0 + c4 + 3 < Nc) ? bp[3] : 0.f;
            }
            Bs[kk][c4 + 0] = v.x;
            Bs[kk][c4 + 1] = v.y;
            Bs[kk][c4 + 2] = v.z;
            Bs[kk][c4 + 3] = v.w;
        }
        __syncthreads();
        #pragma unroll
        for (int k = 0; k < 16; ++k) {
            float a0 = As[k][tr * 4 + 0];
            float a1 = As[k][tr * 4 + 1];
            float a2 = As[k][tr * 4 + 2];
            float a3 = As[k][tr * 4 + 3];
            float b0 = Bs[k][tc * 4 + 0];
            float b1 = Bs[k][tc * 4 + 1];
            float b2 = Bs[k][tc * 4 + 2];
            float b3 = Bs[k][tc * 4 + 3];
            acc[0][0] += a0 * b0; acc[0][1] += a0 * b1; acc[0][2] += a0 * b2; acc[0][3] += a0 * b3;
            acc[1][0] += a1 * b0; acc[1][1] += a1 * b1; acc[1][2] += a1 * b2; acc[1][3] += a1 * b3;
            acc[2][0] += a2 * b0; acc[2][1] += a2 * b1; acc[2][2] += a2 * b2; acc[2][3] += a2 * b3;
            acc[3][0] += a3 * b0; acc[3][1] += a3 * b1; acc[3][2] += a3 * b2; acc[3][3] += a3 * b3;
        }
        __syncthreads();
    }
    #pragma unroll
    for (int i = 0; i < 4; ++i) {
        const int r = row0 + tr * 4 + i;
        #pragma unroll
        for (int j = 0; j < 4; ++j) {
            const int c = col0 + tc * 4 + j;
            if (c < Nc) C[(size_t)r * Nc + c] = acc[i][j];
        }
    }
}

// ---------------- per-row dots: es[i] = h[i]·a_self, en[i] = h[i]·a_neigh ----------------
__global__ __launch_bounds__(256)
void scores_kernel(const float* __restrict__ h, const float* __restrict__ a_self,
                   const float* __restrict__ a_neigh, float* __restrict__ es,
                   float* __restrict__ en, int d)
{
    const int i = blockIdx.x;
    const float* hr = h + (size_t)i * d;
    float ps = 0.f, pn = 0.f;
    for (int k = threadIdx.x; k < d; k += 256) {
        const float hv = hr[k];
        ps += hv * a_self[k];
        pn += hv * a_neigh[k];
    }
    #pragma unroll
    for (int off = 32; off; off >>= 1) {
        ps += __shfl_down(ps, off);
        pn += __shfl_down(pn, off);
    }
    __shared__ float ss[4], sn[4];
    const int lane = threadIdx.x & 63, w = threadIdx.x >> 6;
    if (lane == 0) { ss[w] = ps; sn[w] = pn; }
    __syncthreads();
    if (threadIdx.x == 0) {
        es[i] = ss[0] + ss[1] + ss[2] + ss[3];
        en[i] = sn[0] + sn[1] + sn[2] + sn[3];
    }
}

// ---------------- attention row: masked leaky-relu(e*M), softmax, write normalized ----------------
__global__ __launch_bounds__(256)
void attn_kernel(const float* __restrict__ adj, const float* __restrict__ Mm,
                 const float* __restrict__ es, const float* __restrict__ en,
                 float* __restrict__ attn)
{
    __shared__ float p[NROW];
    __shared__ float red[4];
    const int i = blockIdx.x;
    const float esi = es[i];
    const float* adjr = adj + (size_t)i * NROW;
    const float* Mr   = Mm  + (size_t)i * NROW;
    const int lane = threadIdx.x & 63, w = threadIdx.x >> 6;

    float lmax = -3.0e38f;
    for (int j = threadIdx.x; j < NROW; j += 256) {
        const float a = adjr[j];
        float e;
        if (a > 0.f) {
            const float t = (esi + en[j]) * Mr[j];
            e = (t >= 0.f) ? t : ALPHA_SLOPE * t;
        } else {
            e = -3.0e38f;
        }
        p[j] = e;
        lmax = fmaxf(lmax, e);
    }
    #pragma unroll
    for (int off = 32; off; off >>= 1) lmax = fmaxf(lmax, __shfl_down(lmax, off));
    if (lane == 0) red[w] = lmax;
    __syncthreads();
    const float m = fmaxf(fmaxf(red[0], red[1]), fmaxf(red[2], red[3]));
    __syncthreads();

    float lsum = 0.f;
    for (int j = threadIdx.x; j < NROW; j += 256) {
        const float e = p[j];
        const float pe = (e <= -1.0e38f) ? 0.f : expf(e - m);
        p[j] = pe;
        lsum += pe;
    }
    #pragma unroll
    for (int off = 32; off; off >>= 1) lsum += __shfl_down(lsum, off);
    __syncthreads();
    if (lane == 0) red[w] = lsum;
    __syncthreads();
    const float s = red[0] + red[1] + red[2] + red[3];
    const float inv = 1.0f / s;
    for (int j = threadIdx.x; j < NROW; j += 256)
        attn[(size_t)i * NROW + j] = p[j] * inv;
}

// ---------------- elementwise ----------------
__global__ void elu_kernel(const float* __restrict__ in, float* __restrict__ out, int n)
{
    for (int i = blockIdx.x * 256 + threadIdx.x; i < n; i += gridDim.x * 256) {
        const float x = in[i];
        out[i] = (x > 0.f) ? x : expm1f(x);
    }
}

__global__ void mix_kernel(const float* __restrict__ h, const float* __restrict__ enc,
                           float* __restrict__ out, int n)
{
    for (int i = blockIdx.x * 256 + threadIdx.x; i < n; i += gridDim.x * 256) {
        out[i] = 0.6f * h[i] + 0.4f * enc[i];
    }
}

// ---------------- tmat[512,16] = h1[4096,512]^T @ h4[4096,16] ----------------
__global__ __launch_bounds__(256)
void ata_kernel(const float* __restrict__ h1, const float* __restrict__ h4,
                float* __restrict__ tmat)
{
    const int r = blockIdx.x;   // 0..511
    float acc[16];
    #pragma unroll
    for (int c = 0; c < 16; ++c) acc[c] = 0.f;
    for (int n = threadIdx.x; n < NROW; n += 256) {
        const float hv = h1[(size_t)n * 512 + r];
        const float* h4r = h4 + (size_t)n * 16;
        #pragma unroll
        for (int c = 0; c < 16; ++c) acc[c] += hv * h4r[c];
    }
    #pragma unroll
    for (int c = 0; c < 16; ++c)
        #pragma unroll
        for (int off = 32; off; off >>= 1) acc[c] += __shfl_down(acc[c], off);
    __shared__ float red[4][16];
    const int lane = threadIdx.x & 63, w = threadIdx.x >> 6;
    if (lane == 0)
        for (int c = 0; c < 16; ++c) red[w][c] = acc[c];
    __syncthreads();
    if (threadIdx.x < 16)
        tmat[r * 16 + threadIdx.x] = red[0][threadIdx.x] + red[1][threadIdx.x] +
                                     red[2][threadIdx.x] + red[3][threadIdx.x];
}

// ---------------- row L2 normalize: out[i,:] = z1[i,:] / max(||z1[i,:]||, 1e-12) ----------------
__global__ __launch_bounds__(64)
void norm_kernel(const float* __restrict__ z1, float* __restrict__ out)
{
    const int i = blockIdx.x;
    const int lane = threadIdx.x;
    const float v = (lane < 16) ? z1[(size_t)i * 16 + lane] : 0.f;
    float sq = v * v;
    #pragma unroll
    for (int off = 32; off; off >>= 1) sq += __shfl_down(sq, off);
    const float tot = __shfl(sq, 0);
    const float inv = 1.0f / fmaxf(sqrtf(tot), 1e-12f);
    if (lane < 16) out[(size_t)i * 16 + lane] = v * inv;
}

extern "C" void kernel_launch(void* const* d_in, const int* in_sizes, int n_in,
                              void* d_out, int out_size, void* d_ws, size_t ws_size,
                              hipStream_t stream)
{
    const float* x    = (const float*)d_in[0];
    const float* adj  = (const float*)d_in[1];
    const float* Mm   = (const float*)d_in[2];
    const float* enc1 = (const float*)d_in[3];
    const float* enc2 = (const float*)d_in[4];
    const float* emb  = (const float*)d_in[5];
    const float* W1  = (const float*)d_in[6];
    const float* as1 = (const float*)d_in[7];
    const float* an1 = (const float*)d_in[8];
    const float* W2  = (const float*)d_in[9];
    const float* as2 = (const float*)d_in[10];
    const float* an2 = (const float*)d_in[11];
    const float* W3  = (const float*)d_in[12];
    const float* as3 = (const float*)d_in[13];
    const float* an3 = (const float*)d_in[14];
    const float* W4  = (const float*)d_in[15];
    const float* as4 = (const float*)d_in[16];
    const float* an4 = (const float*)d_in[17];
    float* out = (float*)d_out;

    float* ws = (float*)d_ws;
    size_t off = 0;
    float* attnbuf = ws + off; off += (size_t)NROW * NROW;  // 64 MB
    float* hW   = ws + off;    off += (size_t)NROW * 512;
    float* hp   = ws + off;    off += (size_t)NROW * 512;
    float* h1   = ws + off;    off += (size_t)NROW * 512;
    float* inb  = ws + off;    off += (size_t)NROW * 512;
    float* es   = ws + off;    off += NROW;
    float* en   = ws + off;    off += NROW;
    float* tmat = ws + off;    off += 512 * 16;
    float* z1   = ws + off;    off += (size_t)NROW * 16;
    (void)ws_size; (void)in_sizes; (void)n_in; (void)out_size;

    auto gemm = [&](const float* A, const float* B, float* C, int M, int Nc, int K) {
        dim3 grid((Nc + 63) / 64, (M + 63) / 64);
        gemm_f32<<<grid, 256, 0, stream>>>(A, B, C, M, Nc, K);
    };

    // ---- layer 1: in = x [4096,1024] -> h [4096,512]
    gemm(x, W1, hW, NROW, 512, 1024);
    scores_kernel<<<NROW, 256, 0, stream>>>(hW, as1, an1, es, en, 512);
    attn_kernel<<<NROW, 256, 0, stream>>>(adj, Mm, es, en, attnbuf);
    gemm(attnbuf, hW, hp, NROW, 512, NROW);
    elu_kernel<<<2048, 256, 0, stream>>>(hp, h1, NROW * 512);
    mix_kernel<<<2048, 256, 0, stream>>>(h1, enc1, inb, NROW * 512);

    // ---- layer 2: [4096,512] -> [4096,256]
    gemm(inb, W2, hW, NROW, 256, 512);
    scores_kernel<<<NROW, 256, 0, stream>>>(hW, as2, an2, es, en, 256);
    attn_kernel<<<NROW, 256, 0, stream>>>(adj, Mm, es, en, attnbuf);
    gemm(attnbuf, hW, hp, NROW, 256, NROW);
    elu_kernel<<<1024, 256, 0, stream>>>(hp, hp, NROW * 256);
    mix_kernel<<<1024, 256, 0, stream>>>(hp, enc2, inb, NROW * 256);

    // ---- layer 3: [4096,256] -> [4096,64]
    gemm(inb, W3, hW, NROW, 64, 256);
    scores_kernel<<<NROW, 256, 0, stream>>>(hW, as3, an3, es, en, 64);
    attn_kernel<<<NROW, 256, 0, stream>>>(adj, Mm, es, en, attnbuf);
    gemm(attnbuf, hW, hp, NROW, 64, NROW);
    elu_kernel<<<512, 256, 0, stream>>>(hp, hp, NROW * 64);
    mix_kernel<<<512, 256, 0, stream>>>(hp, emb, inb, NROW * 64);

    // ---- layer 4: [4096,64] -> [4096,16]
    gemm(inb, W4, hW, NROW, 16, 64);
    scores_kernel<<<NROW, 256, 0, stream>>>(hW, as4, an4, es, en, 16);
    attn_kernel<<<NROW, 256, 0, stream>>>(adj, Mm, es, en, attnbuf);
    gemm(attnbuf, hW, hp, NROW, 16, NROW);
    elu_kernel<<<256, 256, 0, stream>>>(hp, hp, NROW * 16);   // hp = h4

    // ---- z1 = h1 @ (h1^T @ h4);  z = rownorm(z1)
    ata_kernel<<<512, 256, 0, stream>>>(h1, hp, tmat);
    gemm(h1, tmat, z1, NROW, 16, 512);
    norm_kernel<<<NROW, 64, 0, stream>>>(z1, out);
}

// Round 4
// 462.135 us; speedup vs baseline: 4.0049x; 4.0049x over previous
//
// round 3: bf16 MFMA GEMM path + bf16 attn matrix + Mmask precompute
#include <hip/hip_runtime.h>
#include <math.h>

#define NROW 4096
#define ALPHA_SLOPE 0.2f

typedef __attribute__((ext_vector_type(8))) short bf16x8;
typedef __attribute__((ext_vector_type(4))) float f32x4;

__device__ __forceinline__ ushort f2bf(float f) {
    union { float f; unsigned u; } v; v.f = f;
    unsigned r = v.u + 0x7fffu + ((v.u >> 16) & 1u);   // RNE
    return (ushort)(r >> 16);
}
__device__ __forceinline__ float bf2f(ushort u) {
    union { unsigned u; float f; } v; v.u = ((unsigned)u) << 16;
    return v.f;
}

// ================= bf16 MFMA GEMM =================
// C[M][N] f32 = A[M][K] bf16 row-major  @  Bt[N][K] bf16 row-major (i.e. B^T input)
// 128x64 tile, 256 threads = 4 waves (2x2), mfma_f32_16x16x32_bf16, BK=32.
// Requires: M%128==0, K%32==0. N arbitrary (B rows clamped, C cols guarded).
#define GBM 128
#define GBN 64
#define GBK 32

__global__ __launch_bounds__(256)
void gemm_bf16(const ushort* __restrict__ A, const ushort* __restrict__ Bt,
               float* __restrict__ C, int M, int N, int K)
{
    __shared__ ushort As[GBM * GBK];   // 512 slots of 16B, slot (r,c): chunk swizzled
    __shared__ ushort Bs[GBN * GBK];   // 256 slots
    const int tid  = threadIdx.x;
    const int lane = tid & 63;
    const int wave = tid >> 6;
    const int wr = wave >> 1, wc = wave & 1;
    const int row0 = blockIdx.y * GBM;
    const int col0 = blockIdx.x * GBN;

    f32x4 acc[4][2];
    #pragma unroll
    for (int i = 0; i < 4; ++i)
        #pragma unroll
        for (int j = 0; j < 2; ++j) acc[i][j] = (f32x4){0.f, 0.f, 0.f, 0.f};

    // staging: A slots s=tid and s=tid+256 (r=s>>2, c=s&3); B slot s=tid.
    const int rA0 = tid >> 2,        cA0 = tid & 3;
    const int rA1 = (tid + 256) >> 2, cA1 = tid & 3;
    const int rB  = tid >> 2,        cB  = tid & 3;
    const int rBg = (col0 + rB < N) ? (col0 + rB) : (N - 1);   // clamp (N<tile)

    const ushort* pA0 = A  + (size_t)(row0 + rA0) * K + cA0 * 8;
    const ushort* pA1 = A  + (size_t)(row0 + rA1) * K + cA1 * 8;
    const ushort* pB  = Bt + (size_t)rBg * K + cB * 8;

    // swizzled LDS dest offsets (ushort units): slot = r*4 + (c ^ ((r>>1)&3))
    const int dA0 = (rA0 * 4 + (cA0 ^ ((rA0 >> 1) & 3))) * 8;
    const int dA1 = (rA1 * 4 + (cA1 ^ ((rA1 >> 1) & 3))) * 8;
    const int dB  = (rB  * 4 + (cB  ^ ((rB  >> 1) & 3))) * 8;

    // frag geometry
    const int arow = wr * 64 + (lane & 15);   // + mi*16
    const int brow = wc * 32 + (lane & 15);   // + ni*16
    const int acg  = lane >> 4;               // k-chunk 0..3

    // prefetch k0 = 0
    bf16x8 vA0 = *(const bf16x8*)(pA0);
    bf16x8 vA1 = *(const bf16x8*)(pA1);
    bf16x8 vB  = *(const bf16x8*)(pB);

    for (int k0 = 0; k0 < K; k0 += GBK) {
        __syncthreads();                       // prior reads of LDS complete
        *(bf16x8*)(As + dA0) = vA0;
        *(bf16x8*)(As + dA1) = vA1;
        *(bf16x8*)(Bs + dB)  = vB;
        __syncthreads();
        if (k0 + GBK < K) {                    // prefetch next tile (overlaps MFMA)
            vA0 = *(const bf16x8*)(pA0 + k0 + GBK);
            vA1 = *(const bf16x8*)(pA1 + k0 + GBK);
            vB  = *(const bf16x8*)(pB  + k0 + GBK);
        }
        bf16x8 af[4], bfr[2];
        #pragma unroll
        for (int mi = 0; mi < 4; ++mi) {
            const int r = arow + mi * 16;
            af[mi] = *(const bf16x8*)(As + (r * 4 + (acg ^ ((r >> 1) & 3))) * 8);
        }
        #pragma unroll
        for (int ni = 0; ni < 2; ++ni) {
            const int r = brow + ni * 16;
            bfr[ni] = *(const bf16x8*)(Bs + (r * 4 + (acg ^ ((r >> 1) & 3))) * 8);
        }
        #pragma unroll
        for (int mi = 0; mi < 4; ++mi)
            #pragma unroll
            for (int ni = 0; ni < 2; ++ni)
                acc[mi][ni] = __builtin_amdgcn_mfma_f32_16x16x32_bf16(
                    af[mi], bfr[ni], acc[mi][ni], 0, 0, 0);
    }

    // epilogue: C row = (lane>>4)*4 + j, col = lane&15  [m89-verified layout]
    const int crow  = row0 + wr * 64 + (lane >> 4) * 4;
    const int ccol0 = col0 + wc * 32 + (lane & 15);
    #pragma unroll
    for (int mi = 0; mi < 4; ++mi)
        #pragma unroll
        for (int ni = 0; ni < 2; ++ni) {
            const int cc = ccol0 + ni * 16;
            if (cc < N) {
                #pragma unroll
                for (int j = 0; j < 4; ++j)
                    C[(size_t)(crow + mi * 16 + j) * N + cc] = acc[mi][ni][j];
            }
        }
}

// ================= f32 GEMM (kept for tiny z1 gemm) =================
__global__ __launch_bounds__(256)
void gemm_f32(const float* __restrict__ A, const float* __restrict__ B,
              float* __restrict__ C, int M, int Nc, int K)
{
    __shared__ float As[16][65];
    __shared__ float Bs[16][65];
    const int tid = threadIdx.x;
    const int tr = tid >> 4;
    const int tc = tid & 15;
    const int row0 = blockIdx.y * 64;
    const int col0 = blockIdx.x * 64;
    float acc[4][4] = {{0.f}};

    for (int k0 = 0; k0 < K; k0 += 16) {
        {
            const int r  = tid >> 2;
            const int c4 = (tid & 3) * 4;
            const float* ap = A + (size_t)(row0 + r) * K + k0 + c4;
            const float4 v = *reinterpret_cast<const float4*>(ap);
            As[c4 + 0][r] = v.x; As[c4 + 1][r] = v.y;
            As[c4 + 2][r] = v.z; As[c4 + 3][r] = v.w;
        }
        {
            const int kk = tid >> 4;
            const int c4 = (tid & 15) * 4;
            const float* bp = B + (size_t)(k0 + kk) * Nc + col0 + c4;
            float4 v;
            if (col0 + c4 + 3 < Nc) {
                v = *reinterpret_cast<const float4*>(bp);
            } else {
                v.x = (col0 + c4 + 0 < Nc) ? bp[0] : 0.f;
                v.y = (col0 + c4 + 1 < Nc) ? bp[1] : 0.f;
                v.z = (col0 + c4 + 2 < Nc) ? bp[2] : 0.f;
                v.w = (col0 + c4 + 3 < Nc) ? bp[3] : 0.f;
            }
            Bs[kk][c4 + 0] = v.x; Bs[kk][c4 + 1] = v.y;
            Bs[kk][c4 + 2] = v.z; Bs[kk][c4 + 3] = v.w;
        }
        __syncthreads();
        #pragma unroll
        for (int k = 0; k < 16; ++k) {
            float a0 = As[k][tr*4+0], a1 = As[k][tr*4+1], a2 = As[k][tr*4+2], a3 = As[k][tr*4+3];
            float b0 = Bs[k][tc*4+0], b1 = Bs[k][tc*4+1], b2 = Bs[k][tc*4+2], b3 = Bs[k][tc*4+3];
            acc[0][0]+=a0*b0; acc[0][1]+=a0*b1; acc[0][2]+=a0*b2; acc[0][3]+=a0*b3;
            acc[1][0]+=a1*b0; acc[1][1]+=a1*b1; acc[1][2]+=a1*b2; acc[1][3]+=a1*b3;
            acc[2][0]+=a2*b0; acc[2][1]+=a2*b1; acc[2][2]+=a2*b2; acc[2][3]+=a2*b3;
            acc[3][0]+=a3*b0; acc[3][1]+=a3*b1; acc[3][2]+=a3*b2; acc[3][3]+=a3*b3;
        }
        __syncthreads();
    }
    #pragma unroll
    for (int i = 0; i < 4; ++i) {
        const int r = row0 + tr * 4 + i;
        #pragma unroll
        for (int j = 0; j < 4; ++j) {
            const int c = col0 + tc * 4 + j;
            if (c < Nc) C[(size_t)r * Nc + c] = acc[i][j];
        }
    }
}

// ================= transpose f32 [R][C] -> bf16 [C][R] =================
__global__ __launch_bounds__(256)
void transpose_bf16(const float* __restrict__ in, ushort* __restrict__ out, int R, int C)
{
    __shared__ float t[32][33];
    const int r0 = blockIdx.y * 32, c0 = blockIdx.x * 32;
    const int j = threadIdx.x & 31;
    for (int i = threadIdx.x >> 5; i < 32; i += 8)
        if (r0 + i < R && c0 + j < C)
            t[i][j] = in[(size_t)(r0 + i) * C + c0 + j];
    __syncthreads();
    for (int i = threadIdx.x >> 5; i < 32; i += 8)
        if (c0 + i < C && r0 + j < R)
            out[(size_t)(c0 + i) * R + r0 + j] = f2bf(t[j][i]);
}

// ================= f32 -> bf16 convert (vectorized) =================
__global__ void conv_bf16(const float4* __restrict__ in, ushort4* __restrict__ out, int n4)
{
    for (int i = blockIdx.x * 256 + threadIdx.x; i < n4; i += gridDim.x * 256) {
        const float4 v = in[i];
        ushort4 o;
        o.x = f2bf(v.x); o.y = f2bf(v.y); o.z = f2bf(v.z); o.w = f2bf(v.w);
        out[i] = o;
    }
}

// ================= Mmask = adj>0 ? M : -1, as bf16 =================
__global__ void mmask_kernel(const float4* __restrict__ adj, const float4* __restrict__ M,
                             ushort4* __restrict__ out, int n4)
{
    for (int i = blockIdx.x * 256 + threadIdx.x; i < n4; i += gridDim.x * 256) {
        const float4 a = adj[i];
        const float4 m = M[i];
        ushort4 o;
        o.x = f2bf(a.x > 0.f ? m.x : -1.f);
        o.y = f2bf(a.y > 0.f ? m.y : -1.f);
        o.z = f2bf(a.z > 0.f ? m.z : -1.f);
        o.w = f2bf(a.w > 0.f ? m.w : -1.f);
        out[i] = o;
    }
}

// ================= per-row dots =================
__global__ __launch_bounds__(256)
void scores_kernel(const float* __restrict__ h, const float* __restrict__ a_self,
                   const float* __restrict__ a_neigh, float* __restrict__ es,
                   float* __restrict__ en, int d)
{
    const int i = blockIdx.x;
    const float* hr = h + (size_t)i * d;
    float ps = 0.f, pn = 0.f;
    for (int k = threadIdx.x; k < d; k += 256) {
        const float hv = hr[k];
        ps += hv * a_self[k];
        pn += hv * a_neigh[k];
    }
    #pragma unroll
    for (int off = 32; off; off >>= 1) {
        ps += __shfl_down(ps, off);
        pn += __shfl_down(pn, off);
    }
    __shared__ float ss[4], sn[4];
    const int lane = threadIdx.x & 63, w = threadIdx.x >> 6;
    if (lane == 0) { ss[w] = ps; sn[w] = pn; }
    __syncthreads();
    if (threadIdx.x == 0) {
        es[i] = ss[0] + ss[1] + ss[2] + ss[3];
        en[i] = sn[0] + sn[1] + sn[2] + sn[3];
    }
}

// ================= attention row softmax -> bf16 attn =================
__global__ __launch_bounds__(256)
void attn_v2(const ushort* __restrict__ Mmaskb, const float* __restrict__ es,
             const float* __restrict__ en, ushort* __restrict__ attnb)
{
    __shared__ float p[NROW];
    __shared__ float red[4];
    const int i = blockIdx.x;
    const float esi = es[i];
    const ushort4* Mr = (const ushort4*)(Mmaskb + (size_t)i * NROW);
    const float4*  E4 = (const float4*)en;
    const int tid = threadIdx.x, lane = tid & 63, w = tid >> 6;

    float lmax = -3.0e38f;
    for (int t = tid; t < NROW / 4; t += 256) {
        const ushort4 m4 = Mr[t];
        const float4  e4 = E4[t];
        const ushort ms[4] = {m4.x, m4.y, m4.z, m4.w};
        const float  ev[4] = {e4.x, e4.y, e4.z, e4.w};
        #pragma unroll
        for (int c = 0; c < 4; ++c) {
            const float mv = bf2f(ms[c]);
            float e;
            if (mv < 0.f) e = -3.0e38f;
            else {
                const float tt = (esi + ev[c]) * mv;
                e = (tt >= 0.f) ? tt : ALPHA_SLOPE * tt;
            }
            p[t * 4 + c] = e;
            lmax = fmaxf(lmax, e);
        }
    }
    #pragma unroll
    for (int off = 32; off; off >>= 1) lmax = fmaxf(lmax, __shfl_down(lmax, off));
    if (lane == 0) red[w] = lmax;
    __syncthreads();
    const float m = fmaxf(fmaxf(red[0], red[1]), fmaxf(red[2], red[3]));
    __syncthreads();

    float lsum = 0.f;
    for (int t = tid; t < NROW; t += 256) {
        const float e = p[t];
        const float pe = (e <= -1.0e38f) ? 0.f : __expf(e - m);
        p[t] = pe;
        lsum += pe;
    }
    #pragma unroll
    for (int off = 32; off; off >>= 1) lsum += __shfl_down(lsum, off);
    __syncthreads();
    if (lane == 0) red[w] = lsum;
    __syncthreads();
    const float inv = 1.0f / (red[0] + red[1] + red[2] + red[3]);
    ushort4* Ar = (ushort4*)(attnb + (size_t)i * NROW);
    for (int t = tid; t < NROW / 4; t += 256) {
        ushort4 o;
        o.x = f2bf(p[t*4+0] * inv);
        o.y = f2bf(p[t*4+1] * inv);
        o.z = f2bf(p[t*4+2] * inv);
        o.w = f2bf(p[t*4+3] * inv);
        Ar[t] = o;
    }
}

// ================= elu + optional mix: outb=bf16(0.6*elu+0.4*enc), outf=elu =================
__global__ void elu_mix(const float4* __restrict__ hp, const float4* __restrict__ enc,
                        ushort4* __restrict__ outb, float4* __restrict__ outf, int n4)
{
    for (int i = blockIdx.x * 256 + threadIdx.x; i < n4; i += gridDim.x * 256) {
        const float4 v = hp[i];
        float4 h;
        h.x = (v.x > 0.f) ? v.x : expm1f(v.x);
        h.y = (v.y > 0.f) ? v.y : expm1f(v.y);
        h.z = (v.z > 0.f) ? v.z : expm1f(v.z);
        h.w = (v.w > 0.f) ? v.w : expm1f(v.w);
        if (outf) outf[i] = h;
        if (outb) {
            const float4 e = enc[i];
            ushort4 o;
            o.x = f2bf(0.6f * h.x + 0.4f * e.x);
            o.y = f2bf(0.6f * h.y + 0.4f * e.y);
            o.z = f2bf(0.6f * h.z + 0.4f * e.z);
            o.w = f2bf(0.6f * h.w + 0.4f * e.w);
            outb[i] = o;
        }
    }
}

// ================= tmat[512][16] = h1^T @ h4 =================
__global__ __launch_bounds__(256)
void ata_kernel(const float* __restrict__ h1, const float* __restrict__ h4,
                float* __restrict__ tmat)
{
    const int r = blockIdx.x;
    float acc[16];
    #pragma unroll
    for (int c = 0; c < 16; ++c) acc[c] = 0.f;
    for (int n = threadIdx.x; n < NROW; n += 256) {
        const float hv = h1[(size_t)n * 512 + r];
        const float* h4r = h4 + (size_t)n * 16;
        #pragma unroll
        for (int c = 0; c < 16; ++c) acc[c] += hv * h4r[c];
    }
    #pragma unroll
    for (int c = 0; c < 16; ++c)
        #pragma unroll
        for (int off = 32; off; off >>= 1) acc[c] += __shfl_down(acc[c], off);
    __shared__ float red[4][16];
    const int lane = threadIdx.x & 63, w = threadIdx.x >> 6;
    if (lane == 0)
        for (int c = 0; c < 16; ++c) red[w][c] = acc[c];
    __syncthreads();
    if (threadIdx.x < 16)
        tmat[r * 16 + threadIdx.x] = red[0][threadIdx.x] + red[1][threadIdx.x] +
                                     red[2][threadIdx.x] + red[3][threadIdx.x];
}

// ================= row L2 normalize =================
__global__ __launch_bounds__(64)
void norm_kernel(const float* __restrict__ z1, float* __restrict__ out)
{
    const int i = blockIdx.x;
    const int lane = threadIdx.x;
    const float v = (lane < 16) ? z1[(size_t)i * 16 + lane] : 0.f;
    float sq = v * v;
    #pragma unroll
    for (int off = 32; off; off >>= 1) sq += __shfl_down(sq, off);
    const float tot = __shfl(sq, 0);
    const float inv = 1.0f / fmaxf(sqrtf(tot), 1e-12f);
    if (lane < 16) out[(size_t)i * 16 + lane] = v * inv;
}

extern "C" void kernel_launch(void* const* d_in, const int* in_sizes, int n_in,
                              void* d_out, int out_size, void* d_ws, size_t ws_size,
                              hipStream_t stream)
{
    const float* x    = (const float*)d_in[0];
    const float* adj  = (const float*)d_in[1];
    const float* Mm   = (const float*)d_in[2];
    const float* enc1 = (const float*)d_in[3];
    const float* enc2 = (const float*)d_in[4];
    const float* emb  = (const float*)d_in[5];
    const float* W1  = (const float*)d_in[6];
    const float* as1 = (const float*)d_in[7];
    const float* an1 = (const float*)d_in[8];
    const float* W2  = (const float*)d_in[9];
    const float* as2 = (const float*)d_in[10];
    const float* an2 = (const float*)d_in[11];
    const float* W3  = (const float*)d_in[12];
    const float* as3 = (const float*)d_in[13];
    const float* an3 = (const float*)d_in[14];
    const float* W4  = (const float*)d_in[15];
    const float* as4 = (const float*)d_in[16];
    const float* an4 = (const float*)d_in[17];
    float* out = (float*)d_out;
    (void)in_sizes; (void)n_in; (void)out_size; (void)ws_size;

    char* ws = (char*)d_ws;
    size_t off = 0;
    auto alloc = [&](size_t bytes) { char* p = ws + off; off += (bytes + 255) & ~(size_t)255; return p; };

    ushort* attnb  = (ushort*)alloc((size_t)NROW * NROW * 2);   // 33.5 MB (also hosts xb)
    ushort* Mmaskb = (ushort*)alloc((size_t)NROW * NROW * 2);   // 33.5 MB
    float*  hW     = (float*) alloc((size_t)NROW * 512 * 4);    // 8.4 MB (also GEMM2 out)
    ushort* hWT    = (ushort*)alloc((size_t)512 * NROW * 2);    // 4.2 MB
    float*  h1     = (float*) alloc((size_t)NROW * 512 * 4);    // 8.4 MB
    ushort* inb    = (ushort*)alloc((size_t)NROW * 512 * 2);    // 4.2 MB
    float*  h4     = (float*) alloc((size_t)NROW * 16 * 4);
    ushort* W1t    = (ushort*)alloc((size_t)512 * 1024 * 2);
    ushort* W2t    = (ushort*)alloc((size_t)256 * 512 * 2);
    ushort* W3t    = (ushort*)alloc((size_t)64 * 256 * 2);
    ushort* W4t    = (ushort*)alloc((size_t)16 * 64 * 2);
    float*  es     = (float*) alloc(NROW * 4);
    float*  en     = (float*) alloc(NROW * 4);
    float*  tmat   = (float*) alloc(512 * 16 * 4);
    float*  z1     = (float*) alloc((size_t)NROW * 16 * 4);
    ushort* xb     = attnb;   // alias: xb dead before attnb written

    auto gemmb = [&](const ushort* A, const ushort* Bt, float* C, int M, int N, int K) {
        dim3 grid((N + GBN - 1) / GBN, M / GBM);
        gemm_bf16<<<grid, 256, 0, stream>>>(A, Bt, C, M, N, K);
    };
    auto trans = [&](const float* in, ushort* o, int R, int C) {
        dim3 grid((C + 31) / 32, (R + 31) / 32);
        transpose_bf16<<<grid, 256, 0, stream>>>(in, o, R, C);
    };

    // ---- one-time prep
    conv_bf16<<<2048, 256, 0, stream>>>((const float4*)x, (ushort4*)xb, NROW * 1024 / 4);
    trans(W1, W1t, 1024, 512);
    trans(W2, W2t, 512, 256);
    trans(W3, W3t, 256, 64);
    trans(W4, W4t, 64, 16);
    mmask_kernel<<<2048, 256, 0, stream>>>((const float4*)adj, (const float4*)Mm,
                                           (ushort4*)Mmaskb, NROW * NROW / 4);

    // ---- layer 1: [4096,1024] -> [4096,512]
    gemmb(xb, W1t, hW, NROW, 512, 1024);
    scores_kernel<<<NROW, 256, 0, stream>>>(hW, as1, an1, es, en, 512);
    trans(hW, hWT, NROW, 512);
    attn_v2<<<NROW, 256, 0, stream>>>(Mmaskb, es, en, attnb);
    gemmb(attnb, hWT, hW, NROW, 512, NROW);
    elu_mix<<<2048, 256, 0, stream>>>((const float4*)hW, (const float4*)enc1,
                                      (ushort4*)inb, (float4*)h1, NROW * 512 / 4);

    // ---- layer 2: [4096,512] -> [4096,256]
    gemmb(inb, W2t, hW, NROW, 256, 512);
    scores_kernel<<<NROW, 256, 0, stream>>>(hW, as2, an2, es, en, 256);
    trans(hW, hWT, NROW, 256);
    attn_v2<<<NROW, 256, 0, stream>>>(Mmaskb, es, en, attnb);
    gemmb(attnb, hWT, hW, NROW, 256, NROW);
    elu_mix<<<1024, 256, 0, stream>>>((const float4*)hW, (const float4*)enc2,
                                      (ushort4*)inb, (float4*)nullptr, NROW * 256 / 4);

    // ---- layer 3: [4096,256] -> [4096,64]
    gemmb(inb, W3t, hW, NROW, 64, 256);
    scores_kernel<<<NROW, 256, 0, stream>>>(hW, as3, an3, es, en, 64);
    trans(hW, hWT, NROW, 64);
    attn_v2<<<NROW, 256, 0, stream>>>(Mmaskb, es, en, attnb);
    gemmb(attnb, hWT, hW, NROW, 64, NROW);
    elu_mix<<<512, 256, 0, stream>>>((const float4*)hW, (const float4*)emb,
                                     (ushort4*)inb, (float4*)nullptr, NROW * 64 / 4);

    // ---- layer 4: [4096,64] -> [4096,16]
    gemmb(inb, W4t, hW, NROW, 16, 64);
    scores_kernel<<<NROW, 256, 0, stream>>>(hW, as4, an4, es, en, 16);
    trans(hW, hWT, NROW, 16);
    attn_v2<<<NROW, 256, 0, stream>>>(Mmaskb, es, en, attnb);
    gemmb(attnb, hWT, hW, NROW, 16, NROW);
    elu_mix<<<256, 256, 0, stream>>>((const float4*)hW, (const float4*)nullptr,
                                     (ushort4*)nullptr, (float4*)h4, NROW * 16 / 4);

    // ---- z1 = h1 @ (h1^T @ h4); z = rownorm(z1)
    ata_kernel<<<512, 256, 0, stream>>>(h1, h4, tmat);
    {
        dim3 grid((16 + 63) / 64, NROW / 64);
        gemm_f32<<<grid, 256, 0, stream>>>(h1, tmat, z1, NROW, 16, 512);
    }
    norm_kernel<<<NROW, 64, 0, stream>>>(z1, out);
}

// Round 5
// 379.520 us; speedup vs baseline: 4.8766x; 1.2177x over previous
//
// round 4: split-K gemm_bf16 (occupancy fix: 1 block/CU -> 2+), deterministic partial reduce
#include <hip/hip_runtime.h>
#include <math.h>

#define NROW 4096
#define ALPHA_SLOPE 0.2f

typedef __attribute__((ext_vector_type(8))) short bf16x8;
typedef __attribute__((ext_vector_type(4))) float f32x4;

__device__ __forceinline__ ushort f2bf(float f) {
    union { float f; unsigned u; } v; v.f = f;
    unsigned r = v.u + 0x7fffu + ((v.u >> 16) & 1u);   // RNE
    return (ushort)(r >> 16);
}
__device__ __forceinline__ float bf2f(ushort u) {
    union { unsigned u; float f; } v; v.u = ((unsigned)u) << 16;
    return v.f;
}

// ================= bf16 MFMA GEMM with split-K =================
// C[M][N] f32 = A[M][K] bf16 row-major @ Bt[N][K] bf16 row-major.
// grid.z = splits; block z handles k in [z*Ks, z*Ks+Ks). Last split writes C,
// earlier splits write P + z*M*N. Requires M%128==0, Ks%32==0.
#define GBM 128
#define GBN 64
#define GBK 32

__global__ __launch_bounds__(256)
void gemm_bf16(const ushort* __restrict__ A, const ushort* __restrict__ Bt,
               float* __restrict__ C, float* __restrict__ P,
               int M, int N, int K, int Ks)
{
    __shared__ ushort As[GBM * GBK];
    __shared__ ushort Bs[GBN * GBK];
    const int tid  = threadIdx.x;
    const int lane = tid & 63;
    const int wave = tid >> 6;
    const int wr = wave >> 1, wc = wave & 1;
    const int row0 = blockIdx.y * GBM;
    const int col0 = blockIdx.x * GBN;
    const int z    = blockIdx.z;
    const size_t koff = (size_t)z * Ks;

    f32x4 acc[4][2];
    #pragma unroll
    for (int i = 0; i < 4; ++i)
        #pragma unroll
        for (int j = 0; j < 2; ++j) acc[i][j] = (f32x4){0.f, 0.f, 0.f, 0.f};

    const int rA0 = tid >> 2,         cA0 = tid & 3;
    const int rA1 = (tid + 256) >> 2, cA1 = tid & 3;
    const int rB  = tid >> 2,         cB  = tid & 3;
    const int rBg = (col0 + rB < N) ? (col0 + rB) : (N - 1);

    const ushort* pA0 = A  + (size_t)(row0 + rA0) * K + koff + cA0 * 8;
    const ushort* pA1 = A  + (size_t)(row0 + rA1) * K + koff + cA1 * 8;
    const ushort* pB  = Bt + (size_t)rBg * K + koff + cB * 8;

    const int dA0 = (rA0 * 4 + (cA0 ^ ((rA0 >> 1) & 3))) * 8;
    const int dA1 = (rA1 * 4 + (cA1 ^ ((rA1 >> 1) & 3))) * 8;
    const int dB  = (rB  * 4 + (cB  ^ ((rB  >> 1) & 3))) * 8;

    const int arow = wr * 64 + (lane & 15);
    const int brow = wc * 32 + (lane & 15);
    const int acg  = lane >> 4;

    bf16x8 vA0 = *(const bf16x8*)(pA0);
    bf16x8 vA1 = *(const bf16x8*)(pA1);
    bf16x8 vB  = *(const bf16x8*)(pB);

    for (int k0 = 0; k0 < Ks; k0 += GBK) {
        __syncthreads();
        *(bf16x8*)(As + dA0) = vA0;
        *(bf16x8*)(As + dA1) = vA1;
        *(bf16x8*)(Bs + dB)  = vB;
        __syncthreads();
        if (k0 + GBK < Ks) {
            vA0 = *(const bf16x8*)(pA0 + k0 + GBK);
            vA1 = *(const bf16x8*)(pA1 + k0 + GBK);
            vB  = *(const bf16x8*)(pB  + k0 + GBK);
        }
        bf16x8 af[4], bfr[2];
        #pragma unroll
        for (int mi = 0; mi < 4; ++mi) {
            const int r = arow + mi * 16;
            af[mi] = *(const bf16x8*)(As + (r * 4 + (acg ^ ((r >> 1) & 3))) * 8);
        }
        #pragma unroll
        for (int ni = 0; ni < 2; ++ni) {
            const int r = brow + ni * 16;
            bfr[ni] = *(const bf16x8*)(Bs + (r * 4 + (acg ^ ((r >> 1) & 3))) * 8);
        }
        #pragma unroll
        for (int mi = 0; mi < 4; ++mi)
            #pragma unroll
            for (int ni = 0; ni < 2; ++ni)
                acc[mi][ni] = __builtin_amdgcn_mfma_f32_16x16x32_bf16(
                    af[mi], bfr[ni], acc[mi][ni], 0, 0, 0);
    }

    float* outp = (z == (int)gridDim.z - 1) ? C : (P + (size_t)z * M * N);
    const int crow  = row0 + wr * 64 + (lane >> 4) * 4;
    const int ccol0 = col0 + wc * 32 + (lane & 15);
    #pragma unroll
    for (int mi = 0; mi < 4; ++mi)
        #pragma unroll
        for (int ni = 0; ni < 2; ++ni) {
            const int cc = ccol0 + ni * 16;
            if (cc < N) {
                #pragma unroll
                for (int j = 0; j < 4; ++j)
                    outp[(size_t)(crow + mi * 16 + j) * N + cc] = acc[mi][ni][j];
            }
        }
}

// C[i] += sum_{s<nm1} P[s][i]  (fixed order — deterministic)
__global__ void reduce_k(float4* __restrict__ C, const float4* __restrict__ P,
                         int nm1, int n4)
{
    for (int i = blockIdx.x * 256 + threadIdx.x; i < n4; i += gridDim.x * 256) {
        float4 c = C[i];
        for (int s = 0; s < nm1; ++s) {
            const float4 p = P[(size_t)s * n4 + i];
            c.x += p.x; c.y += p.y; c.z += p.z; c.w += p.w;
        }
        C[i] = c;
    }
}

// ================= f32 GEMM (tiny z1 gemm) =================
__global__ __launch_bounds__(256)
void gemm_f32(const float* __restrict__ A, const float* __restrict__ B,
              float* __restrict__ C, int M, int Nc, int K)
{
    __shared__ float As[16][65];
    __shared__ float Bs[16][65];
    const int tid = threadIdx.x;
    const int tr = tid >> 4;
    const int tc = tid & 15;
    const int row0 = blockIdx.y * 64;
    const int col0 = blockIdx.x * 64;
    float acc[4][4] = {{0.f}};

    for (int k0 = 0; k0 < K; k0 += 16) {
        {
            const int r  = tid >> 2;
            const int c4 = (tid & 3) * 4;
            const float* ap = A + (size_t)(row0 + r) * K + k0 + c4;
            const float4 v = *reinterpret_cast<const float4*>(ap);
            As[c4 + 0][r] = v.x; As[c4 + 1][r] = v.y;
            As[c4 + 2][r] = v.z; As[c4 + 3][r] = v.w;
        }
        {
            const int kk = tid >> 4;
            const int c4 = (tid & 15) * 4;
            const float* bp = B + (size_t)(k0 + kk) * Nc + col0 + c4;
            float4 v;
            if (col0 + c4 + 3 < Nc) {
                v = *reinterpret_cast<const float4*>(bp);
            } else {
                v.x = (col0 + c4 + 0 < Nc) ? bp[0] : 0.f;
                v.y = (col0 + c4 + 1 < Nc) ? bp[1] : 0.f;
                v.z = (col0 + c4 + 2 < Nc) ? bp[2] : 0.f;
                v.w = (col0 + c4 + 3 < Nc) ? bp[3] : 0.f;
            }
            Bs[kk][c4 + 0] = v.x; Bs[kk][c4 + 1] = v.y;
            Bs[kk][c4 + 2] = v.z; Bs[kk][c4 + 3] = v.w;
        }
        __syncthreads();
        #pragma unroll
        for (int k = 0; k < 16; ++k) {
            float a0 = As[k][tr*4+0], a1 = As[k][tr*4+1], a2 = As[k][tr*4+2], a3 = As[k][tr*4+3];
            float b0 = Bs[k][tc*4+0], b1 = Bs[k][tc*4+1], b2 = Bs[k][tc*4+2], b3 = Bs[k][tc*4+3];
            acc[0][0]+=a0*b0; acc[0][1]+=a0*b1; acc[0][2]+=a0*b2; acc[0][3]+=a0*b3;
            acc[1][0]+=a1*b0; acc[1][1]+=a1*b1; acc[1][2]+=a1*b2; acc[1][3]+=a1*b3;
            acc[2][0]+=a2*b0; acc[2][1]+=a2*b1; acc[2][2]+=a2*b2; acc[2][3]+=a2*b3;
            acc[3][0]+=a3*b0; acc[3][1]+=a3*b1; acc[3][2]+=a3*b2; acc[3][3]+=a3*b3;
        }
        __syncthreads();
    }
    #pragma unroll
    for (int i = 0; i < 4; ++i) {
        const int r = row0 + tr * 4 + i;
        #pragma unroll
        for (int j = 0; j < 4; ++j) {
            const int c = col0 + tc * 4 + j;
            if (c < Nc) C[(size_t)r * Nc + c] = acc[i][j];
        }
    }
}

// ================= transpose f32 [R][C] -> bf16 [C][R] =================
__global__ __launch_bounds__(256)
void transpose_bf16(const float* __restrict__ in, ushort* __restrict__ out, int R, int C)
{
    __shared__ float t[32][33];
    const int r0 = blockIdx.y * 32, c0 = blockIdx.x * 32;
    const int j = threadIdx.x & 31;
    for (int i = threadIdx.x >> 5; i < 32; i += 8)
        if (r0 + i < R && c0 + j < C)
            t[i][j] = in[(size_t)(r0 + i) * C + c0 + j];
    __syncthreads();
    for (int i = threadIdx.x >> 5; i < 32; i += 8)
        if (c0 + i < C && r0 + j < R)
            out[(size_t)(c0 + i) * R + r0 + j] = f2bf(t[j][i]);
}

// ================= f32 -> bf16 convert =================
__global__ void conv_bf16(const float4* __restrict__ in, ushort4* __restrict__ out, int n4)
{
    for (int i = blockIdx.x * 256 + threadIdx.x; i < n4; i += gridDim.x * 256) {
        const float4 v = in[i];
        ushort4 o;
        o.x = f2bf(v.x); o.y = f2bf(v.y); o.z = f2bf(v.z); o.w = f2bf(v.w);
        out[i] = o;
    }
}

// ================= Mmask = adj>0 ? M : -1, as bf16 =================
__global__ void mmask_kernel(const float4* __restrict__ adj, const float4* __restrict__ M,
                             ushort4* __restrict__ out, int n4)
{
    for (int i = blockIdx.x * 256 + threadIdx.x; i < n4; i += gridDim.x * 256) {
        const float4 a = adj[i];
        const float4 m = M[i];
        ushort4 o;
        o.x = f2bf(a.x > 0.f ? m.x : -1.f);
        o.y = f2bf(a.y > 0.f ? m.y : -1.f);
        o.z = f2bf(a.z > 0.f ? m.z : -1.f);
        o.w = f2bf(a.w > 0.f ? m.w : -1.f);
        out[i] = o;
    }
}

// ================= per-row dots =================
__global__ __launch_bounds__(256)
void scores_kernel(const float* __restrict__ h, const float* __restrict__ a_self,
                   const float* __restrict__ a_neigh, float* __restrict__ es,
                   float* __restrict__ en, int d)
{
    const int i = blockIdx.x;
    const float* hr = h + (size_t)i * d;
    float ps = 0.f, pn = 0.f;
    for (int k = threadIdx.x; k < d; k += 256) {
        const float hv = hr[k];
        ps += hv * a_self[k];
        pn += hv * a_neigh[k];
    }
    #pragma unroll
    for (int off = 32; off; off >>= 1) {
        ps += __shfl_down(ps, off);
        pn += __shfl_down(pn, off);
    }
    __shared__ float ss[4], sn[4];
    const int lane = threadIdx.x & 63, w = threadIdx.x >> 6;
    if (lane == 0) { ss[w] = ps; sn[w] = pn; }
    __syncthreads();
    if (threadIdx.x == 0) {
        es[i] = ss[0] + ss[1] + ss[2] + ss[3];
        en[i] = sn[0] + sn[1] + sn[2] + sn[3];
    }
}

// ================= attention row softmax -> bf16 attn =================
__global__ __launch_bounds__(256)
void attn_v2(const ushort* __restrict__ Mmaskb, const float* __restrict__ es,
             const float* __restrict__ en, ushort* __restrict__ attnb)
{
    __shared__ float p[NROW];
    __shared__ float red[4];
    const int i = blockIdx.x;
    const float esi = es[i];
    const ushort4* Mr = (const ushort4*)(Mmaskb + (size_t)i * NROW);
    const float4*  E4 = (const float4*)en;
    const int tid = threadIdx.x, lane = tid & 63, w = tid >> 6;

    float lmax = -3.0e38f;
    for (int t = tid; t < NROW / 4; t += 256) {
        const ushort4 m4 = Mr[t];
        const float4  e4 = E4[t];
        const ushort ms[4] = {m4.x, m4.y, m4.z, m4.w};
        const float  ev[4] = {e4.x, e4.y, e4.z, e4.w};
        #pragma unroll
        for (int c = 0; c < 4; ++c) {
            const float mv = bf2f(ms[c]);
            float e;
            if (mv < 0.f) e = -3.0e38f;
            else {
                const float tt = (esi + ev[c]) * mv;
                e = (tt >= 0.f) ? tt : ALPHA_SLOPE * tt;
            }
            p[t * 4 + c] = e;
            lmax = fmaxf(lmax, e);
        }
    }
    #pragma unroll
    for (int off = 32; off; off >>= 1) lmax = fmaxf(lmax, __shfl_down(lmax, off));
    if (lane == 0) red[w] = lmax;
    __syncthreads();
    const float m = fmaxf(fmaxf(red[0], red[1]), fmaxf(red[2], red[3]));
    __syncthreads();

    float lsum = 0.f;
    for (int t = tid; t < NROW; t += 256) {
        const float e = p[t];
        const float pe = (e <= -1.0e38f) ? 0.f : __expf(e - m);
        p[t] = pe;
        lsum += pe;
    }
    #pragma unroll
    for (int off = 32; off; off >>= 1) lsum += __shfl_down(lsum, off);
    __syncthreads();
    if (lane == 0) red[w] = lsum;
    __syncthreads();
    const float inv = 1.0f / (red[0] + red[1] + red[2] + red[3]);
    ushort4* Ar = (ushort4*)(attnb + (size_t)i * NROW);
    for (int t = tid; t < NROW / 4; t += 256) {
        ushort4 o;
        o.x = f2bf(p[t*4+0] * inv);
        o.y = f2bf(p[t*4+1] * inv);
        o.z = f2bf(p[t*4+2] * inv);
        o.w = f2bf(p[t*4+3] * inv);
        Ar[t] = o;
    }
}

// ================= elu + optional mix =================
__global__ void elu_mix(const float4* __restrict__ hp, const float4* __restrict__ enc,
                        ushort4* __restrict__ outb, float4* __restrict__ outf, int n4)
{
    for (int i = blockIdx.x * 256 + threadIdx.x; i < n4; i += gridDim.x * 256) {
        const float4 v = hp[i];
        float4 h;
        h.x = (v.x > 0.f) ? v.x : expm1f(v.x);
        h.y = (v.y > 0.f) ? v.y : expm1f(v.y);
        h.z = (v.z > 0.f) ? v.z : expm1f(v.z);
        h.w = (v.w > 0.f) ? v.w : expm1f(v.w);
        if (outf) outf[i] = h;
        if (outb) {
            const float4 e = enc[i];
            ushort4 o;
            o.x = f2bf(0.6f * h.x + 0.4f * e.x);
            o.y = f2bf(0.6f * h.y + 0.4f * e.y);
            o.z = f2bf(0.6f * h.z + 0.4f * e.z);
            o.w = f2bf(0.6f * h.w + 0.4f * e.w);
            outb[i] = o;
        }
    }
}

// ================= tmat[512][16] = h1^T @ h4 =================
__global__ __launch_bounds__(256)
void ata_kernel(const float* __restrict__ h1, const float* __restrict__ h4,
                float* __restrict__ tmat)
{
    const int r = blockIdx.x;
    float acc[16];
    #pragma unroll
    for (int c = 0; c < 16; ++c) acc[c] = 0.f;
    for (int n = threadIdx.x; n < NROW; n += 256) {
        const float hv = h1[(size_t)n * 512 + r];
        const float* h4r = h4 + (size_t)n * 16;
        #pragma unroll
        for (int c = 0; c < 16; ++c) acc[c] += hv * h4r[c];
    }
    #pragma unroll
    for (int c = 0; c < 16; ++c)
        #pragma unroll
        for (int off = 32; off; off >>= 1) acc[c] += __shfl_down(acc[c], off);
    __shared__ float red[4][16];
    const int lane = threadIdx.x & 63, w = threadIdx.x >> 6;
    if (lane == 0)
        for (int c = 0; c < 16; ++c) red[w][c] = acc[c];
    __syncthreads();
    if (threadIdx.x < 16)
        tmat[r * 16 + threadIdx.x] = red[0][threadIdx.x] + red[1][threadIdx.x] +
                                     red[2][threadIdx.x] + red[3][threadIdx.x];
}

// ================= row L2 normalize =================
__global__ __launch_bounds__(64)
void norm_kernel(const float* __restrict__ z1, float* __restrict__ out)
{
    const int i = blockIdx.x;
    const int lane = threadIdx.x;
    const float v = (lane < 16) ? z1[(size_t)i * 16 + lane] : 0.f;
    float sq = v * v;
    #pragma unroll
    for (int off = 32; off; off >>= 1) sq += __shfl_down(sq, off);
    const float tot = __shfl(sq, 0);
    const float inv = 1.0f / fmaxf(sqrtf(tot), 1e-12f);
    if (lane < 16) out[(size_t)i * 16 + lane] = v * inv;
}

extern "C" void kernel_launch(void* const* d_in, const int* in_sizes, int n_in,
                              void* d_out, int out_size, void* d_ws, size_t ws_size,
                              hipStream_t stream)
{
    const float* x    = (const float*)d_in[0];
    const float* adj  = (const float*)d_in[1];
    const float* Mm   = (const float*)d_in[2];
    const float* enc1 = (const float*)d_in[3];
    const float* enc2 = (const float*)d_in[4];
    const float* emb  = (const float*)d_in[5];
    const float* W1  = (const float*)d_in[6];
    const float* as1 = (const float*)d_in[7];
    const float* an1 = (const float*)d_in[8];
    const float* W2  = (const float*)d_in[9];
    const float* as2 = (const float*)d_in[10];
    const float* an2 = (const float*)d_in[11];
    const float* W3  = (const float*)d_in[12];
    const float* as3 = (const float*)d_in[13];
    const float* an3 = (const float*)d_in[14];
    const float* W4  = (const float*)d_in[15];
    const float* as4 = (const float*)d_in[16];
    const float* an4 = (const float*)d_in[17];
    float* out = (float*)d_out;
    (void)in_sizes; (void)n_in; (void)out_size; (void)ws_size;

    char* ws = (char*)d_ws;
    size_t off = 0;
    auto alloc = [&](size_t bytes) { char* p = ws + off; off += (bytes + 255) & ~(size_t)255; return p; };

    ushort* attnb  = (ushort*)alloc((size_t)NROW * NROW * 2);   // 33.5 MB (also hosts xb)
    ushort* Mmaskb = (ushort*)alloc((size_t)NROW * NROW * 2);   // 33.5 MB
    float*  hW     = (float*) alloc((size_t)NROW * 512 * 4);    // 8.4 MB
    ushort* hWT    = (ushort*)alloc((size_t)512 * NROW * 2);    // 4.2 MB
    float*  h1     = (float*) alloc((size_t)NROW * 512 * 4);    // 8.4 MB
    ushort* inb    = (ushort*)alloc((size_t)NROW * 512 * 2);    // 4.2 MB
    float*  Pbuf   = (float*) alloc((size_t)NROW * 512 * 4);    // 8.4 MB split-K partials
    float*  h4     = (float*) alloc((size_t)NROW * 16 * 4);
    ushort* W1t    = (ushort*)alloc((size_t)512 * 1024 * 2);
    ushort* W2t    = (ushort*)alloc((size_t)256 * 512 * 2);
    ushort* W3t    = (ushort*)alloc((size_t)64 * 256 * 2);
    ushort* W4t    = (ushort*)alloc((size_t)16 * 64 * 2);
    float*  es     = (float*) alloc(NROW * 4);
    float*  en     = (float*) alloc(NROW * 4);
    float*  tmat   = (float*) alloc(512 * 16 * 4);
    float*  z1     = (float*) alloc((size_t)NROW * 16 * 4);
    ushort* xb     = attnb;   // alias: xb dead before attnb written

    // splits chosen so (P bytes = (splits-1)*M*N*4) <= 8.4 MB and blocks*splits >= 256
    auto gemmb = [&](const ushort* A, const ushort* Bt, float* C,
                     int M, int N, int K, int splits) {
        const int Ks = K / splits;               // always divisible by 32 here
        dim3 grid((N + GBN - 1) / GBN, M / GBM, splits);
        gemm_bf16<<<grid, 256, 0, stream>>>(A, Bt, C, Pbuf, M, N, K, Ks);
        if (splits > 1) {
            const int n4 = M * N / 4;
            reduce_k<<<1024, 256, 0, stream>>>((float4*)C, (const float4*)Pbuf,
                                               splits - 1, n4);
        }
    };
    auto trans = [&](const float* in, ushort* o, int R, int C) {
        dim3 grid((C + 31) / 32, (R + 31) / 32);
        transpose_bf16<<<grid, 256, 0, stream>>>(in, o, R, C);
    };

    // ---- one-time prep
    conv_bf16<<<2048, 256, 0, stream>>>((const float4*)x, (ushort4*)xb, NROW * 1024 / 4);
    trans(W1, W1t, 1024, 512);
    trans(W2, W2t, 512, 256);
    trans(W3, W3t, 256, 64);
    trans(W4, W4t, 64, 16);
    mmask_kernel<<<2048, 256, 0, stream>>>((const float4*)adj, (const float4*)Mm,
                                           (ushort4*)Mmaskb, NROW * NROW / 4);

    // ---- layer 1: [4096,1024] -> [4096,512]
    gemmb(xb, W1t, hW, NROW, 512, 1024, 2);          // 512 blocks
    scores_kernel<<<NROW, 256, 0, stream>>>(hW, as1, an1, es, en, 512);
    trans(hW, hWT, NROW, 512);
    attn_v2<<<NROW, 256, 0, stream>>>(Mmaskb, es, en, attnb);
    gemmb(attnb, hWT, hW, NROW, 512, NROW, 2);       // 512 blocks
    elu_mix<<<2048, 256, 0, stream>>>((const float4*)hW, (const float4*)enc1,
                                      (ushort4*)inb, (float4*)h1, NROW * 512 / 4);

    // ---- layer 2: [4096,512] -> [4096,256]
    gemmb(inb, W2t, hW, NROW, 256, 512, 2);          // 256 blocks
    scores_kernel<<<NROW, 256, 0, stream>>>(hW, as2, an2, es, en, 256);
    trans(hW, hWT, NROW, 256);
    attn_v2<<<NROW, 256, 0, stream>>>(Mmaskb, es, en, attnb);
    gemmb(attnb, hWT, hW, NROW, 256, NROW, 2);       // 256 blocks
    elu_mix<<<1024, 256, 0, stream>>>((const float4*)hW, (const float4*)enc2,
                                      (ushort4*)inb, (float4*)nullptr, NROW * 256 / 4);

    // ---- layer 3: [4096,256] -> [4096,64]
    gemmb(inb, W3t, hW, NROW, 64, 256, 8);           // 256 blocks, Ks=32
    scores_kernel<<<NROW, 256, 0, stream>>>(hW, as3, an3, es, en, 64);
    trans(hW, hWT, NROW, 64);
    attn_v2<<<NROW, 256, 0, stream>>>(Mmaskb, es, en, attnb);
    gemmb(attnb, hWT, hW, NROW, 64, NROW, 8);        // 256 blocks, Ks=512
    elu_mix<<<512, 256, 0, stream>>>((const float4*)hW, (const float4*)emb,
                                     (ushort4*)inb, (float4*)nullptr, NROW * 64 / 4);

    // ---- layer 4: [4096,64] -> [4096,16]
    gemmb(inb, W4t, hW, NROW, 16, 64, 2);            // 64 blocks, Ks=32
    scores_kernel<<<NROW, 256, 0, stream>>>(hW, as4, an4, es, en, 16);
    trans(hW, hWT, NROW, 16);
    attn_v2<<<NROW, 256, 0, stream>>>(Mmaskb, es, en, attnb);
    gemmb(attnb, hWT, hW, NROW, 16, NROW, 16);       // 512 blocks, Ks=256
    elu_mix<<<256, 256, 0, stream>>>((const float4*)hW, (const float4*)nullptr,
                                     (ushort4*)nullptr, (float4*)h4, NROW * 16 / 4);

    // ---- z1 = h1 @ (h1^T @ h4); z = rownorm(z1)
    ata_kernel<<<512, 256, 0, stream>>>(h1, h4, tmat);
    {
        dim3 grid((16 + 63) / 64, NROW / 64);
        gemm_f32<<<grid, 256, 0, stream>>>(h1, tmat, z1, NROW, 16, 512);
    }
    norm_kernel<<<NROW, 64, 0, stream>>>(z1, out);
}

// Round 6
// 345.029 us; speedup vs baseline: 5.3641x; 1.1000x over previous
//
// round 6: BK=64 swizzled gemm (templated BN 64/128), deeper split-K, fast mmask, ws guard
#include <hip/hip_runtime.h>
#include <math.h>

#define NROW 4096
#define ALPHA_SLOPE 0.2f

typedef __attribute__((ext_vector_type(8))) short bf16x8;
typedef __attribute__((ext_vector_type(4))) float f32x4;

__device__ __forceinline__ ushort f2bf(float f) {
    union { float f; unsigned u; } v; v.f = f;
    unsigned r = v.u + 0x7fffu + ((v.u >> 16) & 1u);   // RNE
    return (ushort)(r >> 16);
}
__device__ __forceinline__ float bf2f(ushort u) {
    union { unsigned u; float f; } v; v.u = ((unsigned)u) << 16;
    return v.f;
}

// ================= bf16 MFMA GEMM, BK=64, both-sides-swizzled LDS =================
// C[M][N] f32 = A[M][K] bf16 row-major @ Bt[N][K] bf16 row-major (B^T input).
// Tile 128 x BN (BN = NF*32), 4 waves (2x2), BK=64, split-K via grid.z.
// LDS layout: [row][chunk] of 16B chunks; slot s = r*8+c. Source pre-swizzle
// csrc = c ^ (r&7); fragment read uses chunk (Q ^ (r&7)) — same involution
// (rule 21: linear dest + inverse-swz source + swz read).
// Requires M%128==0, Ks%64==0. N arbitrary (clamped rows, guarded cols).
template<int NF>
__global__ __launch_bounds__(256)
void gemm_bf16(const ushort* __restrict__ A, const ushort* __restrict__ Bt,
               float* __restrict__ C, float* __restrict__ P,
               int M, int N, int K, int Ks)
{
    constexpr int BN  = NF * 32;
    constexpr int APT = 4;               // 1024 A slots / 256 thr
    constexpr int BPT = BN * 8 / 256;    // 2 (BN64) or 4 (BN128)
    __shared__ ushort As[128 * 64];      // 16 KB
    __shared__ ushort Bs[BN * 64];       // 8/16 KB
    const int tid  = threadIdx.x;
    const int lane = tid & 63;
    const int wave = tid >> 6;
    const int wr = wave >> 1, wc = wave & 1;
    const int row0 = blockIdx.y * 128;
    const int col0 = blockIdx.x * BN;
    const size_t koff = (size_t)blockIdx.z * Ks;

    f32x4 acc[4][NF];
    #pragma unroll
    for (int i = 0; i < 4; ++i)
        #pragma unroll
        for (int j = 0; j < NF; ++j) acc[i][j] = (f32x4){0.f, 0.f, 0.f, 0.f};

    const ushort* pA[APT]; int dA[APT];
    #pragma unroll
    for (int j = 0; j < APT; ++j) {
        const int s = tid + 256 * j;
        const int r = s >> 3, c = s & 7;
        pA[j] = A + (size_t)(row0 + r) * K + koff + (size_t)(c ^ (r & 7)) * 8;
        dA[j] = s * 8;
    }
    const ushort* pB[BPT]; int dB[BPT];
    #pragma unroll
    for (int j = 0; j < BPT; ++j) {
        const int s = tid + 256 * j;
        const int r = s >> 3, c = s & 7;
        const int rg = (col0 + r < N) ? (col0 + r) : (N - 1);
        pB[j] = Bt + (size_t)rg * K + koff + (size_t)(c ^ (r & 7)) * 8;
        dB[j] = s * 8;
    }

    const int arow0 = wr * 64 + (lane & 15);
    const int brow0 = wc * (BN / 2) + (lane & 15);
    const int acg   = lane >> 4;

    bf16x8 vA[APT], vB[BPT];
    #pragma unroll
    for (int j = 0; j < APT; ++j) vA[j] = *(const bf16x8*)(pA[j]);
    #pragma unroll
    for (int j = 0; j < BPT; ++j) vB[j] = *(const bf16x8*)(pB[j]);

    for (int k0 = 0; k0 < Ks; k0 += 64) {
        __syncthreads();
        #pragma unroll
        for (int j = 0; j < APT; ++j) *(bf16x8*)(As + dA[j]) = vA[j];
        #pragma unroll
        for (int j = 0; j < BPT; ++j) *(bf16x8*)(Bs + dB[j]) = vB[j];
        __syncthreads();
        if (k0 + 64 < Ks) {
            #pragma unroll
            for (int j = 0; j < APT; ++j) vA[j] = *(const bf16x8*)(pA[j] + k0 + 64);
            #pragma unroll
            for (int j = 0; j < BPT; ++j) vB[j] = *(const bf16x8*)(pB[j] + k0 + 64);
        }
        #pragma unroll
        for (int kk = 0; kk < 2; ++kk) {
            const int Q = kk * 4 + acg;
            bf16x8 af[4], bfr[NF];
            #pragma unroll
            for (int mi = 0; mi < 4; ++mi) {
                const int r = arow0 + mi * 16;
                af[mi] = *(const bf16x8*)(As + (r * 8 + (Q ^ (r & 7))) * 8);
            }
            #pragma unroll
            for (int ni = 0; ni < NF; ++ni) {
                const int r = brow0 + ni * 16;
                bfr[ni] = *(const bf16x8*)(Bs + (r * 8 + (Q ^ (r & 7))) * 8);
            }
            #pragma unroll
            for (int mi = 0; mi < 4; ++mi)
                #pragma unroll
                for (int ni = 0; ni < NF; ++ni)
                    acc[mi][ni] = __builtin_amdgcn_mfma_f32_16x16x32_bf16(
                        af[mi], bfr[ni], acc[mi][ni], 0, 0, 0);
        }
    }

    float* outp = (blockIdx.z == gridDim.z - 1) ? C : (P + (size_t)blockIdx.z * M * N);
    const int crow  = row0 + wr * 64 + (lane >> 4) * 4;
    const int ccol0 = col0 + wc * (BN / 2) + (lane & 15);
    #pragma unroll
    for (int mi = 0; mi < 4; ++mi)
        #pragma unroll
        for (int ni = 0; ni < NF; ++ni) {
            const int cc = ccol0 + ni * 16;
            if (cc < N) {
                #pragma unroll
                for (int j = 0; j < 4; ++j)
                    outp[(size_t)(crow + mi * 16 + j) * N + cc] = acc[mi][ni][j];
            }
        }
}

// C[i] += sum_{s<nm1} P[s][i]  (fixed order — deterministic)
__global__ void reduce_k(float4* __restrict__ C, const float4* __restrict__ P,
                         int nm1, int n4)
{
    for (int i = blockIdx.x * 256 + threadIdx.x; i < n4; i += gridDim.x * 256) {
        float4 c = C[i];
        for (int s = 0; s < nm1; ++s) {
            const float4 p = P[(size_t)s * n4 + i];
            c.x += p.x; c.y += p.y; c.z += p.z; c.w += p.w;
        }
        C[i] = c;
    }
}

// ================= f32 GEMM (tiny z1 gemm only) =================
__global__ __launch_bounds__(256)
void gemm_f32(const float* __restrict__ A, const float* __restrict__ B,
              float* __restrict__ C, int M, int Nc, int K)
{
    __shared__ float As[16][65];
    __shared__ float Bs[16][65];
    const int tid = threadIdx.x;
    const int tr = tid >> 4;
    const int tc = tid & 15;
    const int row0 = blockIdx.y * 64;
    const int col0 = blockIdx.x * 64;
    float acc[4][4] = {{0.f}};

    for (int k0 = 0; k0 < K; k0 += 16) {
        {
            const int r  = tid >> 2;
            const int c4 = (tid & 3) * 4;
            const float* ap = A + (size_t)(row0 + r) * K + k0 + c4;
            const float4 v = *reinterpret_cast<const float4*>(ap);
            As[c4 + 0][r] = v.x; As[c4 + 1][r] = v.y;
            As[c4 + 2][r] = v.z; As[c4 + 3][r] = v.w;
        }
        {
            const int kk = tid >> 4;
            const int c4 = (tid & 15) * 4;
            const float* bp = B + (size_t)(k0 + kk) * Nc + col0 + c4;
            float4 v;
            if (col0 + c4 + 3 < Nc) {
                v = *reinterpret_cast<const float4*>(bp);
            } else {
                v.x = (col0 + c4 + 0 < Nc) ? bp[0] : 0.f;
                v.y = (col0 + c4 + 1 < Nc) ? bp[1] : 0.f;
                v.z = (col0 + c4 + 2 < Nc) ? bp[2] : 0.f;
                v.w = (col0 + c4 + 3 < Nc) ? bp[3] : 0.f;
            }
            Bs[kk][c4 + 0] = v.x; Bs[kk][c4 + 1] = v.y;
            Bs[kk][c4 + 2] = v.z; Bs[kk][c4 + 3] = v.w;
        }
        __syncthreads();
        #pragma unroll
        for (int k = 0; k < 16; ++k) {
            float a0 = As[k][tr*4+0], a1 = As[k][tr*4+1], a2 = As[k][tr*4+2], a3 = As[k][tr*4+3];
            float b0 = Bs[k][tc*4+0], b1 = Bs[k][tc*4+1], b2 = Bs[k][tc*4+2], b3 = Bs[k][tc*4+3];
            acc[0][0]+=a0*b0; acc[0][1]+=a0*b1; acc[0][2]+=a0*b2; acc[0][3]+=a0*b3;
            acc[1][0]+=a1*b0; acc[1][1]+=a1*b1; acc[1][2]+=a1*b2; acc[1][3]+=a1*b3;
            acc[2][0]+=a2*b0; acc[2][1]+=a2*b1; acc[2][2]+=a2*b2; acc[2][3]+=a2*b3;
            acc[3][0]+=a3*b0; acc[3][1]+=a3*b1; acc[3][2]+=a3*b2; acc[3][3]+=a3*b3;
        }
        __syncthreads();
    }
    #pragma unroll
    for (int i = 0; i < 4; ++i) {
        const int r = row0 + tr * 4 + i;
        #pragma unroll
        for (int j = 0; j < 4; ++j) {
            const int c = col0 + tc * 4 + j;
            if (c < Nc) C[(size_t)r * Nc + c] = acc[i][j];
        }
    }
}

// ================= transpose f32 [R][C] -> bf16 [C][R] =================
__global__ __launch_bounds__(256)
void transpose_bf16(const float* __restrict__ in, ushort* __restrict__ out, int R, int C)
{
    __shared__ float t[32][33];
    const int r0 = blockIdx.y * 32, c0 = blockIdx.x * 32;
    const int j = threadIdx.x & 31;
    for (int i = threadIdx.x >> 5; i < 32; i += 8)
        if (r0 + i < R && c0 + j < C)
            t[i][j] = in[(size_t)(r0 + i) * C + c0 + j];
    __syncthreads();
    for (int i = threadIdx.x >> 5; i < 32; i += 8)
        if (c0 + i < C && r0 + j < R)
            out[(size_t)(c0 + i) * R + r0 + j] = f2bf(t[j][i]);
}

// ================= f32 -> bf16 convert =================
__global__ void conv_bf16(const float4* __restrict__ in, ushort4* __restrict__ out, int n4)
{
    for (int i = blockIdx.x * 256 + threadIdx.x; i < n4; i += gridDim.x * 256) {
        const float4 v = in[i];
        ushort4 o;
        o.x = f2bf(v.x); o.y = f2bf(v.y); o.z = f2bf(v.z); o.w = f2bf(v.w);
        out[i] = o;
    }
}

// ================= Mmask = adj>0 ? M : -1, bf16. Fixed-index, 4 float4/thread ====
__global__ __launch_bounds__(256)
void mmask_kernel(const float4* __restrict__ adj, const float4* __restrict__ M,
                  ushort4* __restrict__ out)
{
    const int i0 = (blockIdx.x * 256 + threadIdx.x) * 4;
    float4 a[4], m[4];
    #pragma unroll
    for (int u = 0; u < 4; ++u) a[u] = adj[i0 + u];
    #pragma unroll
    for (int u = 0; u < 4; ++u) m[u] = M[i0 + u];
    #pragma unroll
    for (int u = 0; u < 4; ++u) {
        ushort4 o;
        o.x = f2bf(a[u].x > 0.f ? m[u].x : -1.f);
        o.y = f2bf(a[u].y > 0.f ? m[u].y : -1.f);
        o.z = f2bf(a[u].z > 0.f ? m[u].z : -1.f);
        o.w = f2bf(a[u].w > 0.f ? m[u].w : -1.f);
        out[i0 + u] = o;
    }
}

// ================= per-row dots =================
__global__ __launch_bounds__(256)
void scores_kernel(const float* __restrict__ h, const float* __restrict__ a_self,
                   const float* __restrict__ a_neigh, float* __restrict__ es,
                   float* __restrict__ en, int d)
{
    const int i = blockIdx.x;
    const float* hr = h + (size_t)i * d;
    float ps = 0.f, pn = 0.f;
    for (int k = threadIdx.x; k < d; k += 256) {
        const float hv = hr[k];
        ps += hv * a_self[k];
        pn += hv * a_neigh[k];
    }
    #pragma unroll
    for (int off = 32; off; off >>= 1) {
        ps += __shfl_down(ps, off);
        pn += __shfl_down(pn, off);
    }
    __shared__ float ss[4], sn[4];
    const int lane = threadIdx.x & 63, w = threadIdx.x >> 6;
    if (lane == 0) { ss[w] = ps; sn[w] = pn; }
    __syncthreads();
    if (threadIdx.x == 0) {
        es[i] = ss[0] + ss[1] + ss[2] + ss[3];
        en[i] = sn[0] + sn[1] + sn[2] + sn[3];
    }
}

// ================= attention row softmax -> bf16 attn =================
__global__ __launch_bounds__(256)
void attn_v2(const ushort* __restrict__ Mmaskb, const float* __restrict__ es,
             const float* __restrict__ en, ushort* __restrict__ attnb)
{
    __shared__ float p[NROW];
    __shared__ float red[4];
    const int i = blockIdx.x;
    const float esi = es[i];
    const ushort4* Mr = (const ushort4*)(Mmaskb + (size_t)i * NROW);
    const float4*  E4 = (const float4*)en;
    const int tid = threadIdx.x, lane = tid & 63, w = tid >> 6;

    float lmax = -3.0e38f;
    for (int t = tid; t < NROW / 4; t += 256) {
        const ushort4 m4 = Mr[t];
        const float4  e4 = E4[t];
        const ushort ms[4] = {m4.x, m4.y, m4.z, m4.w};
        const float  ev[4] = {e4.x, e4.y, e4.z, e4.w};
        #pragma unroll
        for (int c = 0; c < 4; ++c) {
            const float mv = bf2f(ms[c]);
            float e;
            if (mv < 0.f) e = -3.0e38f;
            else {
                const float tt = (esi + ev[c]) * mv;
                e = (tt >= 0.f) ? tt : ALPHA_SLOPE * tt;
            }
            p[t * 4 + c] = e;
            lmax = fmaxf(lmax, e);
        }
    }
    #pragma unroll
    for (int off = 32; off; off >>= 1) lmax = fmaxf(lmax, __shfl_down(lmax, off));
    if (lane == 0) red[w] = lmax;
    __syncthreads();
    const float m = fmaxf(fmaxf(red[0], red[1]), fmaxf(red[2], red[3]));
    __syncthreads();

    float lsum = 0.f;
    for (int t = tid; t < NROW; t += 256) {
        const float e = p[t];
        const float pe = (e <= -1.0e38f) ? 0.f : __expf(e - m);
        p[t] = pe;
        lsum += pe;
    }
    #pragma unroll
    for (int off = 32; off; off >>= 1) lsum += __shfl_down(lsum, off);
    __syncthreads();
    if (lane == 0) red[w] = lsum;
    __syncthreads();
    const float inv = 1.0f / (red[0] + red[1] + red[2] + red[3]);
    ushort4* Ar = (ushort4*)(attnb + (size_t)i * NROW);
    for (int t = tid; t < NROW / 4; t += 256) {
        ushort4 o;
        o.x = f2bf(p[t*4+0] * inv);
        o.y = f2bf(p[t*4+1] * inv);
        o.z = f2bf(p[t*4+2] * inv);
        o.w = f2bf(p[t*4+3] * inv);
        Ar[t] = o;
    }
}

// ================= elu + optional mix =================
__global__ void elu_mix(const float4* __restrict__ hp, const float4* __restrict__ enc,
                        ushort4* __restrict__ outb, float4* __restrict__ outf, int n4)
{
    for (int i = blockIdx.x * 256 + threadIdx.x; i < n4; i += gridDim.x * 256) {
        const float4 v = hp[i];
        float4 h;
        h.x = (v.x > 0.f) ? v.x : expm1f(v.x);
        h.y = (v.y > 0.f) ? v.y : expm1f(v.y);
        h.z = (v.z > 0.f) ? v.z : expm1f(v.z);
        h.w = (v.w > 0.f) ? v.w : expm1f(v.w);
        if (outf) outf[i] = h;
        if (outb) {
            const float4 e = enc[i];
            ushort4 o;
            o.x = f2bf(0.6f * h.x + 0.4f * e.x);
            o.y = f2bf(0.6f * h.y + 0.4f * e.y);
            o.z = f2bf(0.6f * h.z + 0.4f * e.z);
            o.w = f2bf(0.6f * h.w + 0.4f * e.w);
            outb[i] = o;
        }
    }
}

// ================= tmat[512][16] = h1^T @ h4 =================
__global__ __launch_bounds__(256)
void ata_kernel(const float* __restrict__ h1, const float* __restrict__ h4,
                float* __restrict__ tmat)
{
    const int r = blockIdx.x;
    float acc[16];
    #pragma unroll
    for (int c = 0; c < 16; ++c) acc[c] = 0.f;
    for (int n = threadIdx.x; n < NROW; n += 256) {
        const float hv = h1[(size_t)n * 512 + r];
        const float* h4r = h4 + (size_t)n * 16;
        #pragma unroll
        for (int c = 0; c < 16; ++c) acc[c] += hv * h4r[c];
    }
    #pragma unroll
    for (int c = 0; c < 16; ++c)
        #pragma unroll
        for (int off = 32; off; off >>= 1) acc[c] += __shfl_down(acc[c], off);
    __shared__ float red[4][16];
    const int lane = threadIdx.x & 63, w = threadIdx.x >> 6;
    if (lane == 0)
        for (int c = 0; c < 16; ++c) red[w][c] = acc[c];
    __syncthreads();
    if (threadIdx.x < 16)
        tmat[r * 16 + threadIdx.x] = red[0][threadIdx.x] + red[1][threadIdx.x] +
                                     red[2][threadIdx.x] + red[3][threadIdx.x];
}

// ================= row L2 normalize =================
__global__ __launch_bounds__(64)
void norm_kernel(const float* __restrict__ z1, float* __restrict__ out)
{
    const int i = blockIdx.x;
    const int lane = threadIdx.x;
    const float v = (lane < 16) ? z1[(size_t)i * 16 + lane] : 0.f;
    float sq = v * v;
    #pragma unroll
    for (int off = 32; off; off >>= 1) sq += __shfl_down(sq, off);
    const float tot = __shfl(sq, 0);
    const float inv = 1.0f / fmaxf(sqrtf(tot), 1e-12f);
    if (lane < 16) out[(size_t)i * 16 + lane] = v * inv;
}

extern "C" void kernel_launch(void* const* d_in, const int* in_sizes, int n_in,
                              void* d_out, int out_size, void* d_ws, size_t ws_size,
                              hipStream_t stream)
{
    const float* x    = (const float*)d_in[0];
    const float* adj  = (const float*)d_in[1];
    const float* Mm   = (const float*)d_in[2];
    const float* enc1 = (const float*)d_in[3];
    const float* enc2 = (const float*)d_in[4];
    const float* emb  = (const float*)d_in[5];
    const float* W1  = (const float*)d_in[6];
    const float* as1 = (const float*)d_in[7];
    const float* an1 = (const float*)d_in[8];
    const float* W2  = (const float*)d_in[9];
    const float* as2 = (const float*)d_in[10];
    const float* an2 = (const float*)d_in[11];
    const float* W3  = (const float*)d_in[12];
    const float* as3 = (const float*)d_in[13];
    const float* an3 = (const float*)d_in[14];
    const float* W4  = (const float*)d_in[15];
    const float* as4 = (const float*)d_in[16];
    const float* an4 = (const float*)d_in[17];
    float* out = (float*)d_out;
    (void)in_sizes; (void)n_in; (void)out_size;

    char* ws = (char*)d_ws;
    size_t off = 0;
    auto alloc = [&](size_t bytes) { char* p = ws + off; off += (bytes + 255) & ~(size_t)255; return p; };

    ushort* attnb  = (ushort*)alloc((size_t)NROW * NROW * 2);   // 33.5 MB (also hosts xb)
    ushort* Mmaskb = (ushort*)alloc((size_t)NROW * NROW * 2);   // 33.5 MB
    float*  hW     = (float*) alloc((size_t)NROW * 512 * 4);    // 8.4 MB
    ushort* hWT    = (ushort*)alloc((size_t)512 * NROW * 2);    // 4.2 MB
    float*  h1     = (float*) alloc((size_t)NROW * 512 * 4);    // 8.4 MB
    ushort* inb    = (ushort*)alloc((size_t)NROW * 512 * 2);    // 4.2 MB
    float*  h4     = (float*) alloc((size_t)NROW * 16 * 4);
    ushort* W1t    = (ushort*)alloc((size_t)512 * 1024 * 2);
    ushort* W2t    = (ushort*)alloc((size_t)256 * 512 * 2);
    ushort* W3t    = (ushort*)alloc((size_t)64 * 256 * 2);
    ushort* W4t    = (ushort*)alloc((size_t)16 * 64 * 2);
    float*  es     = (float*) alloc(NROW * 4);
    float*  en     = (float*) alloc(NROW * 4);
    float*  tmat   = (float*) alloc(512 * 16 * 4);
    float*  z1     = (float*) alloc((size_t)NROW * 16 * 4);
    // Pbuf last: size depends on ws headroom. big = 3 partials of 4096x512 f32.
    const size_t pbig = (size_t)3 * NROW * 512 * 4;             // 25.2 MB
    const size_t psml = (size_t)1 * NROW * 512 * 4;             // 8.4 MB
    const bool bigws = ws_size >= off + pbig + (4u << 20);
    float* Pbuf = (float*)alloc(bigws ? pbig : psml);
    ushort* xb = attnb;   // alias: xb dead before attnb written

    auto gemmb = [&](const ushort* A, const ushort* Bt, float* C,
                     int M, int N, int K, int splits) {
        const int Ks = K / splits;                 // Ks % 64 == 0 by schedule
        if (N >= 128) {
            dim3 grid(N / 128, M / 128, splits);
            gemm_bf16<4><<<grid, 256, 0, stream>>>(A, Bt, C, Pbuf, M, N, K, Ks);
        } else {
            dim3 grid(1, M / 128, splits);
            gemm_bf16<2><<<grid, 256, 0, stream>>>(A, Bt, C, Pbuf, M, N, K, Ks);
        }
        if (splits > 1) {
            const int n4 = M * N / 4;
            reduce_k<<<2048, 256, 0, stream>>>((float4*)C, (const float4*)Pbuf,
                                               splits - 1, n4);
        }
    };
    auto trans = [&](const float* in, ushort* o, int R, int C) {
        dim3 grid((C + 31) / 32, (R + 31) / 32);
        transpose_bf16<<<grid, 256, 0, stream>>>(in, o, R, C);
    };

    // split schedule: targets >=256 blocks/dispatch, Pbuf-capacity aware
    const int s_xW1  = 2;
    const int s_att1 = bigws ? 4 : 2;
    const int s_inW2 = bigws ? 4 : 2;
    const int s_att2 = bigws ? 4 : 2;
    const int s_inW3 = 4;                 // 3 partials x 1 MB
    const int s_att3 = 8;                 // 7 x 1 MB
    const int s_inW4 = 1;
    const int s_att4 = 8;                 // 7 x 0.26 MB

    // ---- one-time prep
    conv_bf16<<<2048, 256, 0, stream>>>((const float4*)x, (ushort4*)xb, NROW * 1024 / 4);
    trans(W1, W1t, 1024, 512);
    trans(W2, W2t, 512, 256);
    trans(W3, W3t, 256, 64);
    trans(W4, W4t, 64, 16);
    mmask_kernel<<<4096, 256, 0, stream>>>((const float4*)adj, (const float4*)Mm,
                                           (ushort4*)Mmaskb);

    // ---- layer 1: [4096,1024] -> [4096,512]
    gemmb(xb, W1t, hW, NROW, 512, 1024, s_xW1);
    scores_kernel<<<NROW, 256, 0, stream>>>(hW, as1, an1, es, en, 512);
    trans(hW, hWT, NROW, 512);
    attn_v2<<<NROW, 256, 0, stream>>>(Mmaskb, es, en, attnb);
    gemmb(attnb, hWT, hW, NROW, 512, NROW, s_att1);
    elu_mix<<<2048, 256, 0, stream>>>((const float4*)hW, (const float4*)enc1,
                                      (ushort4*)inb, (float4*)h1, NROW * 512 / 4);

    // ---- layer 2: [4096,512] -> [4096,256]
    gemmb(inb, W2t, hW, NROW, 256, 512, s_inW2);
    scores_kernel<<<NROW, 256, 0, stream>>>(hW, as2, an2, es, en, 256);
    trans(hW, hWT, NROW, 256);
    attn_v2<<<NROW, 256, 0, stream>>>(Mmaskb, es, en, attnb);
    gemmb(attnb, hWT, hW, NROW, 256, NROW, s_att2);
    elu_mix<<<1024, 256, 0, stream>>>((const float4*)hW, (const float4*)enc2,
                                      (ushort4*)inb, (float4*)nullptr, NROW * 256 / 4);

    // ---- layer 3: [4096,256] -> [4096,64]
    gemmb(inb, W3t, hW, NROW, 64, 256, s_inW3);
    scores_kernel<<<NROW, 256, 0, stream>>>(hW, as3, an3, es, en, 64);
    trans(hW, hWT, NROW, 64);
    attn_v2<<<NROW, 256, 0, stream>>>(Mmaskb, es, en, attnb);
    gemmb(attnb, hWT, hW, NROW, 64, NROW, s_att3);
    elu_mix<<<512, 256, 0, stream>>>((const float4*)hW, (const float4*)emb,
                                     (ushort4*)inb, (float4*)nullptr, NROW * 64 / 4);

    // ---- layer 4: [4096,64] -> [4096,16]
    gemmb(inb, W4t, hW, NROW, 16, 64, s_inW4);
    scores_kernel<<<NROW, 256, 0, stream>>>(hW, as4, an4, es, en, 16);
    trans(hW, hWT, NROW, 16);
    attn_v2<<<NROW, 256, 0, stream>>>(Mmaskb, es, en, attnb);
    gemmb(attnb, hWT, hW, NROW, 16, NROW, s_att4);
    elu_mix<<<256, 256, 0, stream>>>((const float4*)hW, (const float4*)nullptr,
                                     (ushort4*)nullptr, (float4*)h4, NROW * 16 / 4);

    // ---- z1 = h1 @ (h1^T @ h4); z = rownorm(z1)
    ata_kernel<<<512, 256, 0, stream>>>(h1, h4, tmat);
    {
        dim3 grid((16 + 63) / 64, NROW / 64);
        gemm_f32<<<grid, 256, 0, stream>>>(h1, tmat, z1, NROW, 16, 512);
    }
    norm_kernel<<<NROW, 64, 0, stream>>>(z1, out);
}